// Round 5
// baseline (1578.471 us; speedup 1.0000x reference)
//
#include <hip/hip_runtime.h>
#include <stdint.h>

typedef __attribute__((ext_vector_type(4))) float  f32x4;
typedef __attribute__((ext_vector_type(8))) short  bf16x8;

#define BATCH   64
#define SRC_LEN 2048
#define HID     1024
#define M_TOT   (BATCH*SRC_LEN)   // 131072

// 256^2 8-phase GEMM geometry
#define BM 256
#define BN 256
#define BK 64

__device__ __forceinline__ short f2bf(float f) {
  unsigned u = __builtin_bit_cast(unsigned, f);
  u += 0x7fffu + ((u >> 16) & 1u);
  return (short)(u >> 16);
}

// ---------------- kernel 0a: w_en_w fp32 -> bf16 (2 MB) ----------------
__global__ void k_convert_w(const float* __restrict__ w, short* __restrict__ wb) {
  int i = (blockIdx.x * 256 + threadIdx.x) * 8;
  f32x4 a = *(const f32x4*)(w + i);
  f32x4 b = *(const f32x4*)(w + i + 4);
  bf16x8 o;
  o[0]=f2bf(a[0]); o[1]=f2bf(a[1]); o[2]=f2bf(a[2]); o[3]=f2bf(a[3]);
  o[4]=f2bf(b[0]); o[5]=f2bf(b[1]); o[6]=f2bf(b[2]); o[7]=f2bf(b[3]);
  *(bf16x8*)(wb + i) = o;
}

// ---------------- kernel 0b: en_output fp32 -> bf16 (256 MB), grid-stride ----------------
__global__ void k_convert_en(const float* __restrict__ in, short* __restrict__ out) {
  size_t stride = (size_t)gridDim.x * 256 * 8;
  size_t base = ((size_t)blockIdx.x * 256 + threadIdx.x) * 8;
  size_t total = (size_t)M_TOT * HID;
  for (; base < total; base += stride) {
    f32x4 a = *(const f32x4*)(in + base);
    f32x4 b = *(const f32x4*)(in + base + 4);
    bf16x8 o;
    o[0]=f2bf(a[0]); o[1]=f2bf(a[1]); o[2]=f2bf(a[2]); o[3]=f2bf(a[3]);
    o[4]=f2bf(b[0]); o[5]=f2bf(b[1]); o[6]=f2bf(b[2]); o[7]=f2bf(b[3]);
    *(bf16x8*)(out + base) = o;
  }
}

// ---------------- kernel 1: bias_all[b][d] = w_en_b + w_de_b + hidden[b]·w_de_w[d] ----------------
__global__ void k_bias(const float* __restrict__ hidden, const float* __restrict__ w_de_w,
                       const float* __restrict__ w_en_b, const float* __restrict__ w_de_b,
                       float* __restrict__ bias_all) {
  __shared__ float hid[HID];
  int b  = blockIdx.x >> 2;
  int dc = blockIdx.x & 3;
  for (int i = threadIdx.x; i < HID; i += 256) hid[i] = hidden[b*HID + i];
  __syncthreads();
  int d = dc*256 + threadIdx.x;
  const f32x4* wrow = (const f32x4*)(w_de_w + (size_t)d*HID);
  float acc = 0.f;
  #pragma unroll 8
  for (int q = 0; q < HID/4; ++q) {
    f32x4 w4 = wrow[q];
    f32x4 h4 = *(const f32x4*)&hid[q*4];
    acc += w4[0]*h4[0] + w4[1]*h4[1] + w4[2]*h4[2] + w4[3]*h4[3];
  }
  bias_all[b*HID + d] = acc + w_en_b[d] + w_de_b[d];
}

// ---------------- kernel 2 (fast): 256^2, 8-wave, 8-phase counted-vmcnt GEMM ----------------
// T1 XCD swizzle, T2 XOR swizzle (0-conflict, verified r3), T3+T4 per-phase interleave with
// counted vmcnt (slice s_p staged during tile t is consumed at phase p of tile t+1;
// per-thread FIFO ledger: boundary vmcnt(4), end-P0 vmcnt(4), end-P1 vmcnt(4); last tile 2->0),
// T5 setprio around each 16-MFMA quadrant.
__global__ void __launch_bounds__(512, 2) k_gemm_score_fast(
    const short* __restrict__ Abf,      // en_output bf16 (M x K)
    const short* __restrict__ Bw,       // w_en bf16 (N x K)
    const float* __restrict__ bias_all, // (BATCH x N)
    const float* __restrict__ v_w,      // (N)
    float* __restrict__ scores)         // (M), pre-zeroed, atomic accumulate
{
  __shared__ short As[2][BM][BK];   // 64 KB
  __shared__ short Bs[2][BN][BK];   // 64 KB

  // T1: 2048 blocks; 256 consecutive ids per XCD; 4 n-siblings share an A panel (L2 reuse)
  int raw  = blockIdx.x;
  int xcd  = raw & 7;
  int idx  = raw >> 3;                  // 0..255
  int mblk = xcd * 64 + (idx >> 2);
  int nblk = idx & 3;
  int m0 = mblk * BM, n0 = nblk * BN;

  int tid  = threadIdx.x;
  int lane = tid & 63;
  int wid  = tid >> 6;           // 8 waves: 2 (m) x 4 (n)
  int wm = wid >> 2, wn = wid & 3;
  int fr  = lane & 15;
  int fko = (lane >> 4) * 8;
  int rsw = (fr & 7) << 3;       // read-side XOR in shorts

  f32x4 acc[8][4] = {};          // wave tile 128x64

  // ---- staging chunk precompute (chunk = 16B; 8 chunks/row of 64 shorts) ----
  // slices: s0 = A rows {0-63,128-191}; s1 = B rows {0-31,64-95,128-159,192-223};
  //         s2 = B rows {32-63,96-127,160-191,224-255}; s3 = A rows {64-127,192-255}
  int cA0 = tid,        cA1 = tid + 1024;   // slice 0
  int cA2 = tid + 512,  cA3 = tid + 1536;   // slice 3
  int gb  = ((tid >> 8) << 9) + (tid & 255);
  int cB0 = gb,         cB1 = gb + 1024;    // slice 1
  int cB2 = gb + 256,   cB3 = gb + 1280;    // slice 2

  #define SOFF(c, rb) ((size_t)((rb) + ((c) >> 3)) * HID + (size_t)((((c) & 7) ^ (((c) >> 3) & 7)) * 8))
  const size_t sA0 = SOFF(cA0, m0), sA1 = SOFF(cA1, m0), sA2 = SOFF(cA2, m0), sA3 = SOFF(cA3, m0);
  const size_t sB0 = SOFF(cB0, n0), sB1 = SOFF(cB1, n0), sB2 = SOFF(cB2, n0), sB3 = SOFF(cB3, n0);
  #undef SOFF

  #define GLD(SRCP, LDSBASE, DOFF) __builtin_amdgcn_global_load_lds( \
      (const __attribute__((address_space(1))) void*)(SRCP), \
      (__attribute__((address_space(3))) void*)((char*)(LDSBASE) + (DOFF)), 16, 0, 0)

  #define STG_A01(OTH, KT) do{ GLD(Abf + sA0 + (KT)*64, &As[OTH][0][0], cA0*16); \
                               GLD(Abf + sA1 + (KT)*64, &As[OTH][0][0], cA1*16); }while(0)
  #define STG_A23(OTH, KT) do{ GLD(Abf + sA2 + (KT)*64, &As[OTH][0][0], cA2*16); \
                               GLD(Abf + sA3 + (KT)*64, &As[OTH][0][0], cA3*16); }while(0)
  #define STG_B01(OTH, KT) do{ GLD(Bw  + sB0 + (KT)*64, &Bs[OTH][0][0], cB0*16); \
                               GLD(Bw  + sB1 + (KT)*64, &Bs[OTH][0][0], cB1*16); }while(0)
  #define STG_B23(OTH, KT) do{ GLD(Bw  + sB2 + (KT)*64, &Bs[OTH][0][0], cB2*16); \
                               GLD(Bw  + sB3 + (KT)*64, &Bs[OTH][0][0], cB3*16); }while(0)

  bf16x8 aF[8], bF[4];
  #define LDA(BUF, MQ) { _Pragma("unroll") for (int mi = 0; mi < 4; ++mi) \
      _Pragma("unroll") for (int kk = 0; kk < 2; ++kk) \
        aF[mi*2+kk] = *(const bf16x8*)&As[BUF][wm*128 + (MQ)*64 + mi*16 + fr][(kk*32 + fko) ^ rsw]; }
  #define LDB(BUF, NQ) { _Pragma("unroll") for (int ni = 0; ni < 2; ++ni) \
      _Pragma("unroll") for (int kk = 0; kk < 2; ++kk) \
        bF[ni*2+kk] = *(const bf16x8*)&Bs[BUF][wn*64 + (NQ)*32 + ni*16 + fr][(kk*32 + fko) ^ rsw]; }
  #define MMQ(MQ, NQ) { _Pragma("unroll") for (int mi = 0; mi < 4; ++mi) \
      _Pragma("unroll") for (int ni = 0; ni < 2; ++ni) \
      _Pragma("unroll") for (int kk = 0; kk < 2; ++kk) \
        acc[(MQ)*4+mi][(NQ)*2+ni] = __builtin_amdgcn_mfma_f32_16x16x32_bf16( \
            aF[mi*2+kk], bF[ni*2+kk], acc[(MQ)*4+mi][(NQ)*2+ni], 0, 0, 0); }

  #define BARR   __builtin_amdgcn_s_barrier()
  #define LG0    asm volatile("s_waitcnt lgkmcnt(0)" ::: "memory")
  #define SCHED0 __builtin_amdgcn_sched_barrier(0)
  #define VMC(N) asm volatile("s_waitcnt vmcnt(" #N ")" ::: "memory")
  #define PR1    __builtin_amdgcn_s_setprio(1)
  #define PR0    __builtin_amdgcn_s_setprio(0)

  // KTILE: 4 phases; LAST is a literal. Stage slice p of tile KT+1 during phase p.
  #define KTILE(BUF, OTH, KT, LAST) do{ \
    /* P0: quadrant (0,0) */ \
    LDA(BUF, 0); LDB(BUF, 0); \
    if (!(LAST)) STG_A01(OTH, (KT)+1); \
    BARR; LG0; SCHED0; PR1; MMQ(0,0); PR0; \
    if (!(LAST)) { VMC(4); } else { VMC(2); } \
    BARR; \
    /* P1: quadrant (0,1) */ \
    LDB(BUF, 1); \
    if (!(LAST)) STG_B01(OTH, (KT)+1); \
    BARR; LG0; SCHED0; PR1; MMQ(0,1); PR0; \
    if (!(LAST)) { VMC(4); } else { VMC(0); } \
    BARR; \
    /* P2: quadrant (1,1) */ \
    LDA(BUF, 1); \
    if (!(LAST)) STG_B23(OTH, (KT)+1); \
    BARR; LG0; SCHED0; PR1; MMQ(1,1); PR0; BARR; \
    /* P3: quadrant (1,0) */ \
    LDB(BUF, 0); \
    if (!(LAST)) STG_A23(OTH, (KT)+1); \
    BARR; LG0; SCHED0; PR1; MMQ(1,0); PR0; \
    if (!(LAST)) { VMC(4); } \
    BARR; \
  }while(0)

  // prologue: stage tile 0 (slices in FIFO order s0,s1,s2,s3), wait first half
  STG_A01(0, 0); STG_B01(0, 0); STG_B23(0, 0); STG_A23(0, 0);
  VMC(4); BARR;

  #pragma unroll 1
  for (int it = 0; it < 8; ++it) {
    KTILE(0, 1, 2*it, false);
    if (it < 7) { KTILE(1, 0, 2*it + 1, false); }
    else        { KTILE(1, 0, 15,       true ); }
  }

  #undef KTILE
  #undef LDA
  #undef LDB
  #undef MMQ

  // Epilogue: energy = tanh(acc + bias), partial score = sum over wave's 64 cols
  int b = m0 >> 11;                          // 2048 rows per batch; 256 | 2048
  float vv[4], bb[4];
  #pragma unroll
  for (int nf = 0; nf < 4; ++nf) {
    int col = n0 + wn*64 + nf*16 + fr;
    vv[nf] = v_w[col];
    bb[nf] = bias_all[b*HID + col];
  }
  #pragma unroll
  for (int mf = 0; mf < 8; ++mf) {
    #pragma unroll
    for (int j = 0; j < 4; ++j) {
      float p = 0.f;
      #pragma unroll
      for (int nf = 0; nf < 4; ++nf)
        p += tanhf(acc[mf][nf][j] + bb[nf]) * vv[nf];
      p += __shfl_xor(p, 1);
      p += __shfl_xor(p, 2);
      p += __shfl_xor(p, 4);
      p += __shfl_xor(p, 8);
      if (fr == 0) {
        int row = wm*128 + mf*16 + ((lane >> 4) << 2) + j;
        atomicAdd(&scores[m0 + row], p);
      }
    }
  }
}

// ---------------- kernel 2 (fallback): 128^2 with in-kernel A conversion (ws too small) ----------------
__global__ void __launch_bounds__(256) k_gemm_score_conv(
    const float* __restrict__ A, const short* __restrict__ Bw,
    const float* __restrict__ bias_all, const float* __restrict__ v_w,
    float* __restrict__ scores)
{
  __shared__ short Asl[128][64];
  __shared__ short Bsl[128][64];
  int raw  = blockIdx.x;
  int xcd  = raw & 7;
  int idx  = raw >> 3;
  int mblk = xcd * (M_TOT/128/8) + (idx >> 3);
  int nblk = idx & 7;
  int m0 = mblk * 128, n0 = nblk * 128;
  int tid  = threadIdx.x;
  int lane = tid & 63;
  int wid  = tid >> 6;
  int wr = wid >> 1, wc = wid & 1;
  int fr  = lane & 15;
  int fko = (lane >> 4) * 8;
  f32x4 acc[4][4] = {};
  int ar = tid >> 1;
  int ac = (tid & 1) * 32;
  const float* aBase = A + (size_t)(m0 + ar) * HID + ac;
  f32x4 aReg[8];
  #pragma unroll
  for (int i = 0; i < 8; ++i) aReg[i] = *(const f32x4*)(aBase + i*4);
  for (int kt = 0; kt < 16; ++kt) {
    __syncthreads();
    #pragma unroll
    for (int g = 0; g < 4; ++g) {
      bf16x8 w;
      w[0]=f2bf(aReg[2*g][0]);   w[1]=f2bf(aReg[2*g][1]);
      w[2]=f2bf(aReg[2*g][2]);   w[3]=f2bf(aReg[2*g][3]);
      w[4]=f2bf(aReg[2*g+1][0]); w[5]=f2bf(aReg[2*g+1][1]);
      w[6]=f2bf(aReg[2*g+1][2]); w[7]=f2bf(aReg[2*g+1][3]);
      *(bf16x8*)&Asl[ar][ac + g*8] = w;
    }
    #pragma unroll
    for (int j = 0; j < 4; ++j) {
      int c = j*256 + tid;
      const short* src = Bw + (size_t)(n0 + (c >> 3)) * HID + kt*64 + (c & 7)*8;
      __builtin_amdgcn_global_load_lds(
          (const __attribute__((address_space(1))) void*)src,
          (__attribute__((address_space(3))) void*)((char*)&Bsl[0][0] + c*16),
          16, 0, 0);
    }
    __syncthreads();
    if (kt + 1 < 16) {
      const float* nxt = aBase + (kt+1)*64;
      #pragma unroll
      for (int i = 0; i < 8; ++i) aReg[i] = *(const f32x4*)(nxt + i*4);
    }
    #pragma unroll
    for (int kk = 0; kk < 2; ++kk) {
      bf16x8 aF[4], bF[4];
      #pragma unroll
      for (int mi = 0; mi < 4; ++mi)
        aF[mi] = *(const bf16x8*)&Asl[wr*64 + mi*16 + fr][kk*32 + fko];
      #pragma unroll
      for (int ni = 0; ni < 4; ++ni)
        bF[ni] = *(const bf16x8*)&Bsl[wc*64 + ni*16 + fr][kk*32 + fko];
      #pragma unroll
      for (int mi = 0; mi < 4; ++mi)
        #pragma unroll
        for (int ni = 0; ni < 4; ++ni)
          acc[mi][ni] = __builtin_amdgcn_mfma_f32_16x16x32_bf16(aF[mi], bF[ni], acc[mi][ni], 0, 0, 0);
    }
  }
  int b = m0 >> 11;
  float vv[4], bb[4];
  #pragma unroll
  for (int ni = 0; ni < 4; ++ni) {
    int col = n0 + wc*64 + ni*16 + fr;
    vv[ni] = v_w[col];
    bb[ni] = bias_all[b*HID + col];
  }
  #pragma unroll
  for (int mi = 0; mi < 4; ++mi) {
    #pragma unroll
    for (int j = 0; j < 4; ++j) {
      float p = 0.f;
      #pragma unroll
      for (int ni = 0; ni < 4; ++ni)
        p += tanhf(acc[mi][ni][j] + bb[ni]) * vv[ni];
      p += __shfl_xor(p, 1);
      p += __shfl_xor(p, 2);
      p += __shfl_xor(p, 4);
      p += __shfl_xor(p, 8);
      if (fr == 0) {
        int row = wr*64 + mi*16 + ((lane >> 4) << 2) + j;
        atomicAdd(&scores[m0 + row], p);
      }
    }
  }
}

// ---------------- kernel 3: in-place softmax over S per batch ----------------
__global__ void k_softmax(float* __restrict__ attn) {
  int b = blockIdx.x;
  float* row = attn + (size_t)b * SRC_LEN;
  int tid = threadIdx.x, lane = tid & 63, wid = tid >> 6;
  __shared__ float red[4];
  float v[8];
  #pragma unroll
  for (int i = 0; i < 8; ++i) v[i] = row[tid + i*256];
  float mx = v[0];
  #pragma unroll
  for (int i = 1; i < 8; ++i) mx = fmaxf(mx, v[i]);
  #pragma unroll
  for (int o = 32; o; o >>= 1) mx = fmaxf(mx, __shfl_xor(mx, o));
  if (lane == 0) red[wid] = mx;
  __syncthreads();
  mx = fmaxf(fmaxf(red[0], red[1]), fmaxf(red[2], red[3]));
  float s = 0.f;
  #pragma unroll
  for (int i = 0; i < 8; ++i) { v[i] = __expf(v[i] - mx); s += v[i]; }
  #pragma unroll
  for (int o = 32; o; o >>= 1) s += __shfl_xor(s, o);
  __syncthreads();
  if (lane == 0) red[wid] = s;
  __syncthreads();
  s = red[0] + red[1] + red[2] + red[3];
  float inv = 1.f / s;
  #pragma unroll
  for (int i = 0; i < 8; ++i) row[tid + i*256] = v[i] * inv;
}

// ---------------- kernel 4: weighted[b,e] = sum_s attn[b,s] * en[b,s,e] ----------------
__global__ void k_weighted(const float* __restrict__ en, const float* __restrict__ attn,
                           float* __restrict__ outw) {
  int b  = blockIdx.x >> 4;
  int sc = blockIdx.x & 15;
  __shared__ float aw[128];
  int tid = threadIdx.x;
  if (tid < 128) aw[tid] = attn[b*SRC_LEN + sc*128 + tid];
  __syncthreads();
  const float* base = en + ((size_t)b*SRC_LEN + sc*128) * HID + tid*4;
  f32x4 acc = {0.f, 0.f, 0.f, 0.f};
  #pragma unroll 8
  for (int s = 0; s < 128; ++s) {
    f32x4 x = *(const f32x4*)(base + (size_t)s*HID);
    float w = aw[s];
    acc[0] += w*x[0]; acc[1] += w*x[1]; acc[2] += w*x[2]; acc[3] += w*x[3];
  }
  float* o = outw + b*HID + tid*4;
  atomicAdd(o+0, acc[0]); atomicAdd(o+1, acc[1]);
  atomicAdd(o+2, acc[2]); atomicAdd(o+3, acc[3]);
}

extern "C" void kernel_launch(void* const* d_in, const int* in_sizes, int n_in,
                              void* d_out, int out_size, void* d_ws, size_t ws_size,
                              hipStream_t stream) {
  const float* hidden = (const float*)d_in[0];
  const float* en     = (const float*)d_in[1];
  const float* w_en_w = (const float*)d_in[2];
  const float* w_en_b = (const float*)d_in[3];
  const float* w_de_w = (const float*)d_in[4];
  const float* w_de_b = (const float*)d_in[5];
  const float* v_w    = (const float*)d_in[6];

  float* outw = (float*)d_out;              // (B, 1, E)
  float* attn = outw + BATCH*HID;           // (B, S) scores -> attention in place

  const size_t en_elems = (size_t)M_TOT * HID;
  const size_t need_fast = en_elems*sizeof(short) + (size_t)HID*HID*sizeof(short)
                         + (size_t)BATCH*HID*sizeof(float);

  hipMemsetAsync(d_out, 0, (size_t)out_size * sizeof(float), stream);

  if (ws_size >= need_fast) {
    short* en_bf    = (short*)d_ws;                       // 256 MB
    short* w_bf     = en_bf + en_elems;                   // 2 MB
    float* bias_all = (float*)(w_bf + (size_t)HID*HID);   // 256 KB

    k_convert_en<<<dim3(2048), dim3(256), 0, stream>>>(en, en_bf);
    k_convert_w<<<dim3(HID*HID/(256*8)), dim3(256), 0, stream>>>(w_en_w, w_bf);
    k_bias<<<dim3(BATCH*4), dim3(256), 0, stream>>>(hidden, w_de_w, w_en_b, w_de_b, bias_all);
    k_gemm_score_fast<<<dim3((M_TOT/BM)*(HID/BN)), dim3(512), 0, stream>>>(en_bf, w_bf, bias_all, v_w, attn);
  } else {
    short* w_bf     = (short*)d_ws;
    float* bias_all = (float*)((char*)d_ws + (size_t)HID*HID*sizeof(short));
    k_convert_w<<<dim3(HID*HID/(256*8)), dim3(256), 0, stream>>>(w_en_w, w_bf);
    k_bias<<<dim3(BATCH*4), dim3(256), 0, stream>>>(hidden, w_de_w, w_en_b, w_de_b, bias_all);
    k_gemm_score_conv<<<dim3((M_TOT/128)*(HID/128)), dim3(256), 0, stream>>>(en, w_bf, bias_all, v_w, attn);
  }

  k_softmax<<<dim3(BATCH), dim3(256), 0, stream>>>(attn);
  k_weighted<<<dim3(BATCH*16), dim3(256), 0, stream>>>(en, attn, outw);
}

// Round 6
// 608.845 us; speedup vs baseline: 2.5926x; 2.5926x over previous
//
#include <hip/hip_runtime.h>
#include <stdint.h>

typedef __attribute__((ext_vector_type(4))) float  f32x4;
typedef __attribute__((ext_vector_type(8))) short  bf16x8;
typedef __attribute__((ext_vector_type(4))) short  s16x4;

#define BATCH   64
#define SRC_LEN 2048
#define HID     1024
#define M_TOT   (BATCH*SRC_LEN)   // 131072

// 256^2 8-phase GEMM geometry
#define BM 256
#define BN 256
#define BK 64

__device__ __forceinline__ short f2bf(float f) {
  unsigned u = __builtin_bit_cast(unsigned, f);
  u += 0x7fffu + ((u >> 16) & 1u);
  return (short)(u >> 16);
}
__device__ __forceinline__ float bf2f(short s) {
  unsigned u = ((unsigned)(unsigned short)s) << 16;
  return __builtin_bit_cast(float, u);
}

// ---------------- kernel 0a: w_en_w fp32 -> bf16 (2 MB) ----------------
__global__ void k_convert_w(const float* __restrict__ w, short* __restrict__ wb) {
  int i = (blockIdx.x * 256 + threadIdx.x) * 8;
  f32x4 a = *(const f32x4*)(w + i);
  f32x4 b = *(const f32x4*)(w + i + 4);
  bf16x8 o;
  o[0]=f2bf(a[0]); o[1]=f2bf(a[1]); o[2]=f2bf(a[2]); o[3]=f2bf(a[3]);
  o[4]=f2bf(b[0]); o[5]=f2bf(b[1]); o[6]=f2bf(b[2]); o[7]=f2bf(b[3]);
  *(bf16x8*)(wb + i) = o;
}

// ---------------- kernel 0b: en_output fp32 -> bf16 (256 MB), grid-stride ----------------
__global__ void k_convert_en(const float* __restrict__ in, short* __restrict__ out) {
  size_t stride = (size_t)gridDim.x * 256 * 8;
  size_t base = ((size_t)blockIdx.x * 256 + threadIdx.x) * 8;
  size_t total = (size_t)M_TOT * HID;
  for (; base < total; base += stride) {
    f32x4 a = *(const f32x4*)(in + base);
    f32x4 b = *(const f32x4*)(in + base + 4);
    bf16x8 o;
    o[0]=f2bf(a[0]); o[1]=f2bf(a[1]); o[2]=f2bf(a[2]); o[3]=f2bf(a[3]);
    o[4]=f2bf(b[0]); o[5]=f2bf(b[1]); o[6]=f2bf(b[2]); o[7]=f2bf(b[3]);
    *(bf16x8*)(out + base) = o;
  }
}

// ---------------- kernel 1: bias_all[b][d] = w_en_b + w_de_b + hidden[b]·w_de_w[d] ----------------
__global__ void k_bias(const float* __restrict__ hidden, const float* __restrict__ w_de_w,
                       const float* __restrict__ w_en_b, const float* __restrict__ w_de_b,
                       float* __restrict__ bias_all) {
  __shared__ float hid[HID];
  int b  = blockIdx.x >> 2;
  int dc = blockIdx.x & 3;
  for (int i = threadIdx.x; i < HID; i += 256) hid[i] = hidden[b*HID + i];
  __syncthreads();
  int d = dc*256 + threadIdx.x;
  const f32x4* wrow = (const f32x4*)(w_de_w + (size_t)d*HID);
  float acc = 0.f;
  #pragma unroll 8
  for (int q = 0; q < HID/4; ++q) {
    f32x4 w4 = wrow[q];
    f32x4 h4 = *(const f32x4*)&hid[q*4];
    acc += w4[0]*h4[0] + w4[1]*h4[1] + w4[2]*h4[2] + w4[3]*h4[3];
  }
  bias_all[b*HID + d] = acc + w_en_b[d] + w_de_b[d];
}

// ---------------- kernel 2 (fast): 256^2, 8-wave, 4-phase/K-tile counted-vmcnt GEMM ----------------
// T1 XCD swizzle, T2 XOR swizzle (0-conflict, r3), T3+T4 per-phase stage interleave with counted
// vmcnt (FIFO ledger: VMC(4) at end of P0/P1/P3; tail tile 2->0; never drain mid-loop),
// T5 setprio. NO sched_barrier / NO explicit lgkmcnt (r5 spill post-mortem: pinning caused
// 2 GB scratch traffic); compiler places its own waitcnts for ds_read->MFMA.
__global__ void __launch_bounds__(512, 1) k_gemm_score_fast(
    const short* __restrict__ Abf,      // en_output bf16 (M x K)
    const short* __restrict__ Bw,       // w_en bf16 (N x K)
    const float* __restrict__ bias_all, // (BATCH x N)
    const float* __restrict__ v_w,      // (N)
    float* __restrict__ scores)         // (M), pre-zeroed, atomic accumulate
{
  __shared__ short As[2][BM][BK];   // 64 KB
  __shared__ short Bs[2][BN][BK];   // 64 KB

  // T1: 2048 blocks; 256 consecutive ids per XCD; 4 n-siblings share an A panel (L2 reuse)
  int raw  = blockIdx.x;
  int xcd  = raw & 7;
  int idx  = raw >> 3;                  // 0..255
  int mblk = xcd * 64 + (idx >> 2);
  int nblk = idx & 3;
  int m0 = mblk * BM, n0 = nblk * BN;

  int tid  = threadIdx.x;
  int lane = tid & 63;
  int wid  = tid >> 6;           // 8 waves: 2 (m) x 4 (n)
  int wm = wid >> 2, wn = wid & 3;
  int fr  = lane & 15;
  int fko = (lane >> 4) * 8;
  int rsw = (fr & 7) << 3;       // read-side XOR in shorts

  f32x4 acc[8][4] = {};          // wave tile 128x64

  // staging chunks (16B each; 8 per row of 64 shorts)
  // FIFO slices per tile: s0=A01 rows{0-63,128-191}, s1=B01 rows{0-31,64-95,128-159,192-223},
  //                       s2=B23 rows{32-63,96-127,160-191,224-255}, s3=A23 rows{64-127,192-255}
  int cA0 = tid,        cA1 = tid + 1024;   // slice 0
  int cA2 = tid + 512,  cA3 = tid + 1536;   // slice 3
  int gb  = ((tid >> 8) << 9) + (tid & 255);
  int cB0 = gb,         cB1 = gb + 1024;    // slice 1
  int cB2 = gb + 256,   cB3 = gb + 1280;    // slice 2

  #define SOFF(c, rb) ((size_t)((rb) + ((c) >> 3)) * HID + (size_t)((((c) & 7) ^ (((c) >> 3) & 7)) * 8))
  const size_t sA0 = SOFF(cA0, m0), sA1 = SOFF(cA1, m0), sA2 = SOFF(cA2, m0), sA3 = SOFF(cA3, m0);
  const size_t sB0 = SOFF(cB0, n0), sB1 = SOFF(cB1, n0), sB2 = SOFF(cB2, n0), sB3 = SOFF(cB3, n0);
  #undef SOFF

  #define GLD(SRCP, LDSBASE, DOFF) __builtin_amdgcn_global_load_lds( \
      (const __attribute__((address_space(1))) void*)(SRCP), \
      (__attribute__((address_space(3))) void*)((char*)(LDSBASE) + (DOFF)), 16, 0, 0)

  #define STG_A01(OTH, KT) do{ GLD(Abf + sA0 + (KT)*64, &As[OTH][0][0], cA0*16); \
                               GLD(Abf + sA1 + (KT)*64, &As[OTH][0][0], cA1*16); }while(0)
  #define STG_A23(OTH, KT) do{ GLD(Abf + sA2 + (KT)*64, &As[OTH][0][0], cA2*16); \
                               GLD(Abf + sA3 + (KT)*64, &As[OTH][0][0], cA3*16); }while(0)
  #define STG_B01(OTH, KT) do{ GLD(Bw  + sB0 + (KT)*64, &Bs[OTH][0][0], cB0*16); \
                               GLD(Bw  + sB1 + (KT)*64, &Bs[OTH][0][0], cB1*16); }while(0)
  #define STG_B23(OTH, KT) do{ GLD(Bw  + sB2 + (KT)*64, &Bs[OTH][0][0], cB2*16); \
                               GLD(Bw  + sB3 + (KT)*64, &Bs[OTH][0][0], cB3*16); }while(0)

  bf16x8 aF[8], bF[4];   // aF reused P0->P1, bF reused P2->P3 (cross-phase live is intentional)
  #define LDA(BUF, MQ) { _Pragma("unroll") for (int mi = 0; mi < 4; ++mi) \
      _Pragma("unroll") for (int kk = 0; kk < 2; ++kk) \
        aF[mi*2+kk] = *(const bf16x8*)&As[BUF][wm*128 + (MQ)*64 + mi*16 + fr][(kk*32 + fko) ^ rsw]; }
  #define LDB(BUF, NQ) { _Pragma("unroll") for (int ni = 0; ni < 2; ++ni) \
      _Pragma("unroll") for (int kk = 0; kk < 2; ++kk) \
        bF[ni*2+kk] = *(const bf16x8*)&Bs[BUF][wn*64 + (NQ)*32 + ni*16 + fr][(kk*32 + fko) ^ rsw]; }
  #define MMQ(MQ, NQ) { _Pragma("unroll") for (int mi = 0; mi < 4; ++mi) \
      _Pragma("unroll") for (int ni = 0; ni < 2; ++ni) \
      _Pragma("unroll") for (int kk = 0; kk < 2; ++kk) \
        acc[(MQ)*4+mi][(NQ)*2+ni] = __builtin_amdgcn_mfma_f32_16x16x32_bf16( \
            aF[mi*2+kk], bF[ni*2+kk], acc[(MQ)*4+mi][(NQ)*2+ni], 0, 0, 0); }

  #define BARR   __builtin_amdgcn_s_barrier()
  #define VMC(N) asm volatile("s_waitcnt vmcnt(" #N ")" ::: "memory")
  #define PR1    __builtin_amdgcn_s_setprio(1)
  #define PR0    __builtin_amdgcn_s_setprio(0)

  // prologue: stage tile 0 in FIFO slice order; wait slices 0,1 (A01,B01)
  STG_A01(0, 0); STG_B01(0, 0); STG_B23(0, 0); STG_A23(0, 0);
  VMC(4); BARR;

  #pragma unroll 1
  for (int kt = 0; kt < 15; ++kt) {
    int buf = kt & 1, oth = buf ^ 1;
    // P0: quadrant (0,0); stage slice0 of kt+1; end-wait covers P1's B23 reads
    LDA(buf, 0); LDB(buf, 0); STG_A01(oth, kt + 1);
    BARR; PR1; MMQ(0, 0); PR0; VMC(4); BARR;
    // P1: quadrant (0,1) (reuses aF); stage slice1; end-wait covers P2's A23 reads
    LDB(buf, 1); STG_B01(oth, kt + 1);
    BARR; PR1; MMQ(0, 1); PR0; VMC(4); BARR;
    // P2: quadrant (1,1) (reuses bF); stage slice2; no wait (P3 reads old B01)
    LDA(buf, 1); STG_B23(oth, kt + 1);
    BARR; PR1; MMQ(1, 1); PR0; BARR;
    // P3: quadrant (1,0) (reuses aF); stage slice3; end-wait covers next P0's A01/B01 reads
    LDB(buf, 0); STG_A23(oth, kt + 1);
    BARR; PR1; MMQ(1, 0); PR0; VMC(4); BARR;
  }
  // tail tile kt=15 (buf=1): no staging; drain 2 -> 0
  LDA(1, 0); LDB(1, 0); BARR; PR1; MMQ(0, 0); PR0; VMC(2); BARR;
  LDB(1, 1);            BARR; PR1; MMQ(0, 1); PR0; VMC(0); BARR;
  LDA(1, 1);            BARR; PR1; MMQ(1, 1); PR0; BARR;
  LDB(1, 0);            BARR; PR1; MMQ(1, 0); PR0;

  #undef LDA
  #undef LDB
  #undef MMQ
  #undef STG_A01
  #undef STG_A23
  #undef STG_B01
  #undef STG_B23
  #undef GLD

  // Epilogue: energy = tanh(acc + bias), partial score = sum over wave's 64 cols
  int b = m0 >> 11;                          // 2048 rows per batch; 256 | 2048
  float vv[4], bb[4];
  #pragma unroll
  for (int nf = 0; nf < 4; ++nf) {
    int col = n0 + wn*64 + nf*16 + fr;
    vv[nf] = v_w[col];
    bb[nf] = bias_all[b*HID + col];
  }
  #pragma unroll
  for (int mf = 0; mf < 8; ++mf) {
    #pragma unroll
    for (int j = 0; j < 4; ++j) {
      float p = 0.f;
      #pragma unroll
      for (int nf = 0; nf < 4; ++nf)
        p += tanhf(acc[mf][nf][j] + bb[nf]) * vv[nf];
      p += __shfl_xor(p, 1);
      p += __shfl_xor(p, 2);
      p += __shfl_xor(p, 4);
      p += __shfl_xor(p, 8);
      if (fr == 0) {
        int row = wm*128 + mf*16 + ((lane >> 4) << 2) + j;
        atomicAdd(&scores[m0 + row], p);
      }
    }
  }
}

// ---------------- kernel 2 (fallback): 128^2 with in-kernel A conversion (ws too small) ----------------
__global__ void __launch_bounds__(256) k_gemm_score_conv(
    const float* __restrict__ A, const short* __restrict__ Bw,
    const float* __restrict__ bias_all, const float* __restrict__ v_w,
    float* __restrict__ scores)
{
  __shared__ short Asl[128][64];
  __shared__ short Bsl[128][64];
  int raw  = blockIdx.x;
  int xcd  = raw & 7;
  int idx  = raw >> 3;
  int mblk = xcd * (M_TOT/128/8) + (idx >> 3);
  int nblk = idx & 7;
  int m0 = mblk * 128, n0 = nblk * 128;
  int tid  = threadIdx.x;
  int lane = tid & 63;
  int wid  = tid >> 6;
  int wr = wid >> 1, wc = wid & 1;
  int fr  = lane & 15;
  int fko = (lane >> 4) * 8;
  f32x4 acc[4][4] = {};
  int ar = tid >> 1;
  int ac = (tid & 1) * 32;
  const float* aBase = A + (size_t)(m0 + ar) * HID + ac;
  f32x4 aReg[8];
  #pragma unroll
  for (int i = 0; i < 8; ++i) aReg[i] = *(const f32x4*)(aBase + i*4);
  for (int kt = 0; kt < 16; ++kt) {
    __syncthreads();
    #pragma unroll
    for (int g = 0; g < 4; ++g) {
      bf16x8 w;
      w[0]=f2bf(aReg[2*g][0]);   w[1]=f2bf(aReg[2*g][1]);
      w[2]=f2bf(aReg[2*g][2]);   w[3]=f2bf(aReg[2*g][3]);
      w[4]=f2bf(aReg[2*g+1][0]); w[5]=f2bf(aReg[2*g+1][1]);
      w[6]=f2bf(aReg[2*g+1][2]); w[7]=f2bf(aReg[2*g+1][3]);
      *(bf16x8*)&Asl[ar][ac + g*8] = w;
    }
    #pragma unroll
    for (int j = 0; j < 4; ++j) {
      int c = j*256 + tid;
      const short* src = Bw + (size_t)(n0 + (c >> 3)) * HID + kt*64 + (c & 7)*8;
      __builtin_amdgcn_global_load_lds(
          (const __attribute__((address_space(1))) void*)src,
          (__attribute__((address_space(3))) void*)((char*)&Bsl[0][0] + c*16),
          16, 0, 0);
    }
    __syncthreads();
    if (kt + 1 < 16) {
      const float* nxt = aBase + (kt+1)*64;
      #pragma unroll
      for (int i = 0; i < 8; ++i) aReg[i] = *(const f32x4*)(nxt + i*4);
    }
    #pragma unroll
    for (int kk = 0; kk < 2; ++kk) {
      bf16x8 aF[4], bF[4];
      #pragma unroll
      for (int mi = 0; mi < 4; ++mi)
        aF[mi] = *(const bf16x8*)&Asl[wr*64 + mi*16 + fr][kk*32 + fko];
      #pragma unroll
      for (int ni = 0; ni < 4; ++ni)
        bF[ni] = *(const bf16x8*)&Bsl[wc*64 + ni*16 + fr][kk*32 + fko];
      #pragma unroll
      for (int mi = 0; mi < 4; ++mi)
        #pragma unroll
        for (int ni = 0; ni < 4; ++ni)
          acc[mi][ni] = __builtin_amdgcn_mfma_f32_16x16x32_bf16(aF[mi], bF[ni], acc[mi][ni], 0, 0, 0);
    }
  }
  int b = m0 >> 11;
  float vv[4], bb[4];
  #pragma unroll
  for (int ni = 0; ni < 4; ++ni) {
    int col = n0 + wc*64 + ni*16 + fr;
    vv[ni] = v_w[col];
    bb[ni] = bias_all[b*HID + col];
  }
  #pragma unroll
  for (int mi = 0; mi < 4; ++mi) {
    #pragma unroll
    for (int j = 0; j < 4; ++j) {
      float p = 0.f;
      #pragma unroll
      for (int ni = 0; ni < 4; ++ni)
        p += tanhf(acc[mi][ni][j] + bb[ni]) * vv[ni];
      p += __shfl_xor(p, 1);
      p += __shfl_xor(p, 2);
      p += __shfl_xor(p, 4);
      p += __shfl_xor(p, 8);
      if (fr == 0) {
        int row = wr*64 + mi*16 + ((lane >> 4) << 2) + j;
        atomicAdd(&scores[m0 + row], p);
      }
    }
  }
}

// ---------------- kernel 3: in-place softmax over S per batch ----------------
__global__ void k_softmax(float* __restrict__ attn) {
  int b = blockIdx.x;
  float* row = attn + (size_t)b * SRC_LEN;
  int tid = threadIdx.x, lane = tid & 63, wid = tid >> 6;
  __shared__ float red[4];
  float v[8];
  #pragma unroll
  for (int i = 0; i < 8; ++i) v[i] = row[tid + i*256];
  float mx = v[0];
  #pragma unroll
  for (int i = 1; i < 8; ++i) mx = fmaxf(mx, v[i]);
  #pragma unroll
  for (int o = 32; o; o >>= 1) mx = fmaxf(mx, __shfl_xor(mx, o));
  if (lane == 0) red[wid] = mx;
  __syncthreads();
  mx = fmaxf(fmaxf(red[0], red[1]), fmaxf(red[2], red[3]));
  float s = 0.f;
  #pragma unroll
  for (int i = 0; i < 8; ++i) { v[i] = __expf(v[i] - mx); s += v[i]; }
  #pragma unroll
  for (int o = 32; o; o >>= 1) s += __shfl_xor(s, o);
  __syncthreads();
  if (lane == 0) red[wid] = s;
  __syncthreads();
  s = red[0] + red[1] + red[2] + red[3];
  float inv = 1.f / s;
  #pragma unroll
  for (int i = 0; i < 8; ++i) row[tid + i*256] = v[i] * inv;
}

// ---------------- kernel 4 (fast): weighted from bf16 en (halves the read traffic) ----------------
__global__ void k_weighted_bf(const short* __restrict__ en_bf, const float* __restrict__ attn,
                              float* __restrict__ outw) {
  int b  = blockIdx.x >> 4;
  int sc = blockIdx.x & 15;
  __shared__ float aw[128];
  int tid = threadIdx.x;
  if (tid < 128) aw[tid] = attn[b*SRC_LEN + sc*128 + tid];
  __syncthreads();
  const short* base = en_bf + ((size_t)b*SRC_LEN + sc*128) * HID + tid*4;
  float a0=0.f, a1=0.f, a2=0.f, a3=0.f;
  #pragma unroll 8
  for (int s = 0; s < 128; ++s) {
    s16x4 x = *(const s16x4*)(base + (size_t)s*HID);
    float w = aw[s];
    a0 += w*bf2f(x[0]); a1 += w*bf2f(x[1]); a2 += w*bf2f(x[2]); a3 += w*bf2f(x[3]);
  }
  float* o = outw + b*HID + tid*4;
  atomicAdd(o+0, a0); atomicAdd(o+1, a1);
  atomicAdd(o+2, a2); atomicAdd(o+3, a3);
}

// ---------------- kernel 4 (fallback): weighted from fp32 en ----------------
__global__ void k_weighted(const float* __restrict__ en, const float* __restrict__ attn,
                           float* __restrict__ outw) {
  int b  = blockIdx.x >> 4;
  int sc = blockIdx.x & 15;
  __shared__ float aw[128];
  int tid = threadIdx.x;
  if (tid < 128) aw[tid] = attn[b*SRC_LEN + sc*128 + tid];
  __syncthreads();
  const float* base = en + ((size_t)b*SRC_LEN + sc*128) * HID + tid*4;
  f32x4 acc = {0.f, 0.f, 0.f, 0.f};
  #pragma unroll 8
  for (int s = 0; s < 128; ++s) {
    f32x4 x = *(const f32x4*)(base + (size_t)s*HID);
    float w = aw[s];
    acc[0] += w*x[0]; acc[1] += w*x[1]; acc[2] += w*x[2]; acc[3] += w*x[3];
  }
  float* o = outw + b*HID + tid*4;
  atomicAdd(o+0, acc[0]); atomicAdd(o+1, acc[1]);
  atomicAdd(o+2, acc[2]); atomicAdd(o+3, acc[3]);
}

extern "C" void kernel_launch(void* const* d_in, const int* in_sizes, int n_in,
                              void* d_out, int out_size, void* d_ws, size_t ws_size,
                              hipStream_t stream) {
  const float* hidden = (const float*)d_in[0];
  const float* en     = (const float*)d_in[1];
  const float* w_en_w = (const float*)d_in[2];
  const float* w_en_b = (const float*)d_in[3];
  const float* w_de_w = (const float*)d_in[4];
  const float* w_de_b = (const float*)d_in[5];
  const float* v_w    = (const float*)d_in[6];

  float* outw = (float*)d_out;              // (B, 1, E)
  float* attn = outw + BATCH*HID;           // (B, S) scores -> attention in place

  const size_t en_elems = (size_t)M_TOT * HID;
  const size_t need_fast = en_elems*sizeof(short) + (size_t)HID*HID*sizeof(short)
                         + (size_t)BATCH*HID*sizeof(float);

  hipMemsetAsync(d_out, 0, (size_t)out_size * sizeof(float), stream);

  if (ws_size >= need_fast) {
    short* en_bf    = (short*)d_ws;                       // 256 MB
    short* w_bf     = en_bf + en_elems;                   // 2 MB
    float* bias_all = (float*)(w_bf + (size_t)HID*HID);   // 256 KB

    k_convert_en<<<dim3(2048), dim3(256), 0, stream>>>(en, en_bf);
    k_convert_w<<<dim3(HID*HID/(256*8)), dim3(256), 0, stream>>>(w_en_w, w_bf);
    k_bias<<<dim3(BATCH*4), dim3(256), 0, stream>>>(hidden, w_de_w, w_en_b, w_de_b, bias_all);
    k_gemm_score_fast<<<dim3((M_TOT/BM)*(HID/BN)), dim3(512), 0, stream>>>(en_bf, w_bf, bias_all, v_w, attn);
    k_softmax<<<dim3(BATCH), dim3(256), 0, stream>>>(attn);
    k_weighted_bf<<<dim3(BATCH*16), dim3(256), 0, stream>>>(en_bf, attn, outw);
  } else {
    short* w_bf     = (short*)d_ws;
    float* bias_all = (float*)((char*)d_ws + (size_t)HID*HID*sizeof(short));
    k_convert_w<<<dim3(HID*HID/(256*8)), dim3(256), 0, stream>>>(w_en_w, w_bf);
    k_bias<<<dim3(BATCH*4), dim3(256), 0, stream>>>(hidden, w_de_w, w_en_b, w_de_b, bias_all);
    k_gemm_score_conv<<<dim3((M_TOT/128)*(HID/128)), dim3(256), 0, stream>>>(en, w_bf, bias_all, v_w, attn);
    k_softmax<<<dim3(BATCH), dim3(256), 0, stream>>>(attn);
    k_weighted<<<dim3(BATCH*16), dim3(256), 0, stream>>>(en, attn, outw);
  }
}